// Round 1
// baseline (3122.230 us; speedup 1.0000x reference)
//
#include <hip/hip_runtime.h>
#include <cstdint>
#include <cstddef>

// Problem constants
#define BB 16
#define CIN 512
#define HWN 4096   // 64*64
#define C8 64
#define C2 256
#define MM 1024    // pooled positions 32*32

// ---------------------------------------------------------------------------
// conv1x1 + relu: out[b, oc0+o, n] = relu(bias + sum_c W[oc,c]*x[b,c,n])
// block: 256 threads over n; each thread holds 64 oc accumulators.
// Weight indices are wave-uniform -> scalar loads (s_load) feeding v_fmac.
// ---------------------------------------------------------------------------
template<int Cin>
__global__ __launch_bounds__(256) void conv_relu_k(
    const float* __restrict__ x, const float* __restrict__ Wt,
    const float* __restrict__ bias, float* __restrict__ out, int CoutTotal) {
  const int t = threadIdx.x;
  const int n = blockIdx.x * 256 + t;
  const int oc0 = blockIdx.y * 64;
  const int b = blockIdx.z;
  const float* xb = x + ((size_t)b * Cin << 12);
  float acc[64];
#pragma unroll
  for (int o = 0; o < 64; ++o) acc[o] = 0.f;
  for (int c = 0; c < Cin; c += 4) {
    float x0 = xb[((size_t)(c + 0) << 12) + n];
    float x1 = xb[((size_t)(c + 1) << 12) + n];
    float x2 = xb[((size_t)(c + 2) << 12) + n];
    float x3 = xb[((size_t)(c + 3) << 12) + n];
#pragma unroll
    for (int o = 0; o < 64; ++o) {
      const float* wr = Wt + (size_t)(oc0 + o) * Cin + c;
      acc[o] = fmaf(wr[0], x0, acc[o]);
      acc[o] = fmaf(wr[1], x1, acc[o]);
      acc[o] = fmaf(wr[2], x2, acc[o]);
      acc[o] = fmaf(wr[3], x3, acc[o]);
    }
  }
  size_t ob = ((size_t)(b * CoutTotal + oc0) << 12) + n;
#pragma unroll
  for (int o = 0; o < 64; ++o) {
    out[ob + ((size_t)o << 12)] = fmaxf(acc[o] + bias[oc0 + o], 0.f);
  }
}

// ---------------------------------------------------------------------------
// phi pooling: in (B,64,4096 full-res) -> out (B,64,1024), 2x2 max
// ---------------------------------------------------------------------------
__global__ __launch_bounds__(256) void pool_phi_k(const float* __restrict__ in,
                                                  float* __restrict__ out) {
  int i = blockIdx.x * 256 + threadIdx.x;  // B*64*1024 total
  int p = i & 1023;
  int bc = i >> 10;
  const float* ib = in + ((size_t)bc << 12) + ((p >> 5) << 7) + ((p & 31) << 1);
  out[i] = fmaxf(fmaxf(ib[0], ib[1]), fmaxf(ib[64], ib[65]));
}

// ---------------------------------------------------------------------------
// g pooling + transpose: in (B,256,4096 full-res) -> out gt (B,1024,256)
// LDS tile transpose so both global read and write are coalesced.
// ---------------------------------------------------------------------------
__global__ __launch_bounds__(256) void pool_gt_k(const float* __restrict__ in,
                                                 float* __restrict__ out) {
  __shared__ float tile[64][65];
  const int t = threadIdx.x;
  const int p0 = blockIdx.x * 64;
  const int c0 = blockIdx.y * 64;
  const int b = blockIdx.z;
#pragma unroll
  for (int it = 0; it < 16; ++it) {
    int idx = it * 256 + t;
    int cl = idx >> 6, pl = idx & 63;
    int p = p0 + pl;
    const float* ib = in + ((size_t)(b * C2 + c0 + cl) << 12)
                         + ((p >> 5) << 7) + ((p & 31) << 1);
    tile[cl][pl] = fmaxf(fmaxf(ib[0], ib[1]), fmaxf(ib[64], ib[65]));
  }
  __syncthreads();
#pragma unroll
  for (int it = 0; it < 16; ++it) {
    int idx = it * 256 + t;
    int pl = idx >> 6, cl = idx & 63;
    out[((size_t)(b << 10) + p0 + pl) * 256 + c0 + cl] = tile[cl][pl];
  }
}

// ---------------------------------------------------------------------------
// attention: per block = (b, 16-query tile)
//   scores[n][m] = sum_c theta[b,c,n]*phi[b,c,m]  (theta row via s_load)
//   softmax over m (per-wave shuffle reduction, 4 rows/wave)
//   o[b,c,n] = sum_m gt[b,m,c]*beta[n][m]
// LDS: 64KB score matrix, reused for the output transpose.
// ---------------------------------------------------------------------------
__global__ __launch_bounds__(256) void attn_k(
    const float* __restrict__ theta, const float* __restrict__ phi,
    const float* __restrict__ gt, float* __restrict__ o) {
  __shared__ __align__(16) float sc[16 * 1024];
  const int t = threadIdx.x;
  const int b = blockIdx.y;
  const int n0 = blockIdx.x * 16;

  // ---- scores ----
  const float* thb = theta + ((size_t)b * C8 << 12) + n0;
  const float* phb = phi + ((size_t)b * C8 << 10);
  float acc[4][16];
#pragma unroll
  for (int mi = 0; mi < 4; ++mi)
#pragma unroll
    for (int j = 0; j < 16; ++j) acc[mi][j] = 0.f;
  for (int c = 0; c < 64; ++c) {
    float th[16];
#pragma unroll
    for (int j = 0; j < 16; ++j) th[j] = thb[((size_t)c << 12) + j];  // uniform -> s_load
    const float* pr = phb + ((size_t)c << 10);
#pragma unroll
    for (int mi = 0; mi < 4; ++mi) {
      float pv = pr[mi * 256 + t];
#pragma unroll
      for (int j = 0; j < 16; ++j) acc[mi][j] = fmaf(pv, th[j], acc[mi][j]);
    }
  }
#pragma unroll
  for (int mi = 0; mi < 4; ++mi)
#pragma unroll
    for (int j = 0; j < 16; ++j)
      sc[j * 1024 + mi * 256 + t] = acc[mi][j];
  __syncthreads();

  // ---- softmax: wave w owns rows 4w..4w+3 ----
  const int w = t >> 6, l = t & 63;
#pragma unroll
  for (int r = 0; r < 4; ++r) {
    const int nn = w * 4 + r;
    float vals[16];
    float mx = -1e30f;
#pragma unroll
    for (int k = 0; k < 16; ++k) {
      vals[k] = sc[nn * 1024 + k * 64 + l];
      mx = fmaxf(mx, vals[k]);
    }
#pragma unroll
    for (int off = 32; off; off >>= 1) mx = fmaxf(mx, __shfl_xor(mx, off));
    float s = 0.f;
#pragma unroll
    for (int k = 0; k < 16; ++k) {
      float e = __expf(vals[k] - mx);
      vals[k] = e;
      s += e;
    }
#pragma unroll
    for (int off = 32; off; off >>= 1) s += __shfl_xor(s, off);
    float inv = 1.f / s;
#pragma unroll
    for (int k = 0; k < 16; ++k) sc[nn * 1024 + k * 64 + l] = vals[k] * inv;
  }
  __syncthreads();

  // ---- PV: thread t = channel c ----
  const float* gtb = gt + (((size_t)b << 10) << 8);
  float oacc[16];
#pragma unroll
  for (int j = 0; j < 16; ++j) oacc[j] = 0.f;
  for (int m4 = 0; m4 < 1024; m4 += 4) {
    float g0 = gtb[(m4 + 0) * 256 + t];
    float g1 = gtb[(m4 + 1) * 256 + t];
    float g2 = gtb[(m4 + 2) * 256 + t];
    float g3 = gtb[(m4 + 3) * 256 + t];
#pragma unroll
    for (int j = 0; j < 16; ++j) {
      float4 b4 = *reinterpret_cast<const float4*>(&sc[j * 1024 + m4]);
      oacc[j] = fmaf(g0, b4.x, oacc[j]);
      oacc[j] = fmaf(g1, b4.y, oacc[j]);
      oacc[j] = fmaf(g2, b4.z, oacc[j]);
      oacc[j] = fmaf(g3, b4.w, oacc[j]);
    }
  }
  __syncthreads();  // everyone done reading sc
#pragma unroll
  for (int j = 0; j < 16; ++j) sc[t * 16 + j] = oacc[j];
  __syncthreads();
  float* obase = o + ((size_t)b * C2 << 12) + n0;
#pragma unroll
  for (int r = 0; r < 16; ++r) {
    int idx = r * 256 + t;
    int cc = idx >> 4, j = idx & 15;
    obase[((size_t)cc << 12) + j] = sc[idx];
  }
}

// ---------------------------------------------------------------------------
// final conv (512 oc, Cin=256) + gamma*relu + residual
// ---------------------------------------------------------------------------
__global__ __launch_bounds__(256) void conv_final_k(
    const float* __restrict__ oin, const float* __restrict__ Wo,
    const float* __restrict__ bo, const float* __restrict__ x,
    const float* __restrict__ gamma, float* __restrict__ out) {
  const int t = threadIdx.x;
  const int n = blockIdx.x * 256 + t;
  const int oc0 = blockIdx.y * 64;
  const int b = blockIdx.z;
  const float* ob = oin + ((size_t)b * C2 << 12);
  float acc[64];
#pragma unroll
  for (int o = 0; o < 64; ++o) acc[o] = 0.f;
  for (int c = 0; c < C2; c += 4) {
    float x0 = ob[((size_t)(c + 0) << 12) + n];
    float x1 = ob[((size_t)(c + 1) << 12) + n];
    float x2 = ob[((size_t)(c + 2) << 12) + n];
    float x3 = ob[((size_t)(c + 3) << 12) + n];
#pragma unroll
    for (int o = 0; o < 64; ++o) {
      const float* wr = Wo + (size_t)(oc0 + o) * C2 + c;
      acc[o] = fmaf(wr[0], x0, acc[o]);
      acc[o] = fmaf(wr[1], x1, acc[o]);
      acc[o] = fmaf(wr[2], x2, acc[o]);
      acc[o] = fmaf(wr[3], x3, acc[o]);
    }
  }
  const float g0 = gamma[0];
  size_t base = ((size_t)(b * CIN + oc0) << 12) + n;
#pragma unroll
  for (int o = 0; o < 64; ++o) {
    float v = fmaxf(acc[o] + bo[oc0 + o], 0.f);
    size_t idx = base + ((size_t)o << 12);
    out[idx] = g0 * v + x[idx];
  }
}

// ---------------------------------------------------------------------------
extern "C" void kernel_launch(void* const* d_in, const int* in_sizes, int n_in,
                              void* d_out, int out_size, void* d_ws, size_t ws_size,
                              hipStream_t stream) {
  const float* x       = (const float*)d_in[0];
  const float* W_theta = (const float*)d_in[1];
  const float* b_theta = (const float*)d_in[2];
  const float* W_phi   = (const float*)d_in[3];
  const float* b_phi   = (const float*)d_in[4];
  const float* W_g     = (const float*)d_in[5];
  const float* b_g     = (const float*)d_in[6];
  const float* W_o     = (const float*)d_in[7];
  const float* b_o     = (const float*)d_in[8];
  const float* gamma   = (const float*)d_in[9];
  float* out = (float*)d_out;
  float* ws  = (float*)d_ws;

  // workspace layout (floats):
  float* theta = ws;              // 16*64*4096   = 4,194,304
  float* phi_p = ws + 4194304;    // 16*64*1024   = 1,048,576
  float* gt    = ws + 5242880;    // 16*1024*256  = 4,194,304
  float* tmp   = ws + 9437184;    // max(full g 16*256*4096, o) = 16,777,216
  // total 26,214,400 floats = 100 MB

  dim3 blk(256);
  // theta conv
  conv_relu_k<512><<<dim3(16, 1, 16), blk, 0, stream>>>(x, W_theta, b_theta, theta, 64);
  // phi conv (full res into tmp) then pool
  conv_relu_k<512><<<dim3(16, 1, 16), blk, 0, stream>>>(x, W_phi, b_phi, tmp, 64);
  pool_phi_k<<<dim3(4096), blk, 0, stream>>>(tmp, phi_p);
  // g conv (full res into tmp) then pool+transpose
  conv_relu_k<512><<<dim3(16, 4, 16), blk, 0, stream>>>(x, W_g, b_g, tmp, 256);
  pool_gt_k<<<dim3(16, 4, 16), blk, 0, stream>>>(tmp, gt);
  // attention -> o (reuses tmp; g_full is dead after pooling)
  attn_k<<<dim3(256, 16), blk, 0, stream>>>(theta, phi_p, gt, tmp);
  // final conv + residual
  conv_final_k<<<dim3(16, 8, 16), blk, 0, stream>>>(tmp, W_o, b_o, x, gamma, out);
}

// Round 2
// 831.510 us; speedup vs baseline: 3.7549x; 3.7549x over previous
//
#include <hip/hip_runtime.h>
#include <cstdint>
#include <cstddef>

#define BB 16
#define CIN 512
#define NPIX 4096   // 64*64
#define C8 64
#define C2 256
#define MM 1024     // pooled positions 32*32

using bf16x8 = __attribute__((ext_vector_type(8))) short;
using f32x4  = __attribute__((ext_vector_type(4))) float;

__device__ __forceinline__ short f2bf(float f) {
  union { float f; unsigned u; } v; v.f = f;
  unsigned r = v.u + 0x7FFFu + ((v.u >> 16) & 1u);
  return (short)(r >> 16);
}
__device__ __forceinline__ bf16x8 ldg8(const short* p) {
  return *reinterpret_cast<const bf16x8*>(p);
}
#define MFMA(a, b, c) __builtin_amdgcn_mfma_f32_16x16x32_bf16(a, b, c, 0, 0, 0)

// ---------------------------------------------------------------------------
// x (B,512,4096) fp32 -> xT (B,4096,512) bf16, LDS tile transpose
// ---------------------------------------------------------------------------
__global__ __launch_bounds__(256) void cast_x_k(const float* __restrict__ x,
                                                short* __restrict__ xT) {
  __shared__ short tile[64][66];
  const int t = threadIdx.x;
  const int n0 = blockIdx.x * 64;
  const int c0 = blockIdx.y * 64;
  const int b  = blockIdx.z;
  const float* xb = x + ((size_t)(b * CIN + c0) << 12) + n0;
#pragma unroll
  for (int it = 0; it < 16; ++it) {
    int idx = it * 256 + t;
    int cl = idx >> 6, nl = idx & 63;
    tile[cl][nl] = f2bf(xb[((size_t)cl << 12) + nl]);
  }
  __syncthreads();
  short* xtb = xT + ((size_t)b << 12) * CIN + (size_t)n0 * CIN + c0;
#pragma unroll
  for (int it = 0; it < 16; ++it) {
    int idx = it * 256 + t;
    int nr = idx >> 6, cc = idx & 63;
    xtb[(size_t)nr * CIN + cc] = tile[cc][nr];
  }
}

// ---------------------------------------------------------------------------
// weight casts: Wtheta(32768) | Wphi(32768) | Wg(131072) | Wo(131072)
// ---------------------------------------------------------------------------
__global__ __launch_bounds__(256) void cast_w_k(const float* __restrict__ wa,
                                                const float* __restrict__ wb,
                                                const float* __restrict__ wc,
                                                const float* __restrict__ wd,
                                                short* __restrict__ out) {
  int i = blockIdx.x * 256 + threadIdx.x;
  float v;
  if (i < 32768) v = wa[i];
  else if (i < 65536) v = wb[i - 32768];
  else if (i < 196608) v = wc[i - 65536];
  else v = wd[i - 196608];
  out[i] = f2bf(v);
}

// ---------------------------------------------------------------------------
// theta conv: thetaT[b][n][oc] = relu(sum_k xT[b][n][k] * W[oc][k] + bias)
// block: 128n x 64oc; wave w: n-tiles {w*32, w*32+16}
// ---------------------------------------------------------------------------
__global__ __launch_bounds__(256) void conv_theta_k(
    const short* __restrict__ xT, const short* __restrict__ Wb,
    const float* __restrict__ bias, short* __restrict__ outT) {
  const int t = threadIdx.x, w = t >> 6, l = t & 63;
  const int lr = l & 15, quad = l >> 4;
  const int nbase = blockIdx.x * 128;
  const int b = blockIdx.y;
  const short* xb = xT + (size_t)b * NPIX * CIN;
  const int nA = nbase + w * 32, nB = nA + 16;
  f32x4 acc[2][4];
#pragma unroll
  for (int i = 0; i < 2; ++i)
#pragma unroll
    for (int j = 0; j < 4; ++j) acc[i][j] = (f32x4){0.f, 0.f, 0.f, 0.f};
  for (int k0 = 0; k0 < CIN; k0 += 32) {
    bf16x8 a0 = ldg8(xb + (size_t)(nA + lr) * CIN + k0 + quad * 8);
    bf16x8 a1 = ldg8(xb + (size_t)(nB + lr) * CIN + k0 + quad * 8);
#pragma unroll
    for (int ot = 0; ot < 4; ++ot) {
      bf16x8 bf = ldg8(Wb + (size_t)(ot * 16 + lr) * CIN + k0 + quad * 8);
      acc[0][ot] = MFMA(a0, bf, acc[0][ot]);
      acc[1][ot] = MFMA(a1, bf, acc[1][ot]);
    }
  }
  short* ob = outT + (size_t)b * NPIX * C8;
#pragma unroll
  for (int nt = 0; nt < 2; ++nt) {
    int nb0 = (nt ? nB : nA) + quad * 4;
#pragma unroll
    for (int ot = 0; ot < 4; ++ot) {
      float bia = bias[ot * 16 + lr];
#pragma unroll
      for (int r = 0; r < 4; ++r) {
        float v = fmaxf(acc[nt][ot][r] + bia, 0.f);
        ob[(size_t)(nb0 + r) * C8 + ot * 16 + lr] = f2bf(v);
      }
    }
  }
}

// ---------------------------------------------------------------------------
// phi conv + fused 2x2 maxpool: phiT[b][m][oc], m = h'*32 + w'
// block covers n=[bx*128, +128) = rows h=2bx,2bx+1; wave: nA=w*16 (h), nB=nA+64 (h+1)
// pool pairs: reg(0,1),(2,3) = w-pairs; accA vs accB = h-pair
// ---------------------------------------------------------------------------
__global__ __launch_bounds__(256) void conv_phi_pool_k(
    const short* __restrict__ xT, const short* __restrict__ Wb,
    const float* __restrict__ bias, short* __restrict__ phiT) {
  const int t = threadIdx.x, w = t >> 6, l = t & 63;
  const int lr = l & 15, quad = l >> 4;
  const int nbase = blockIdx.x * 128;
  const int b = blockIdx.y;
  const short* xb = xT + (size_t)b * NPIX * CIN;
  const int nA = nbase + w * 16, nB = nA + 64;
  f32x4 acc[2][4];
#pragma unroll
  for (int i = 0; i < 2; ++i)
#pragma unroll
    for (int j = 0; j < 4; ++j) acc[i][j] = (f32x4){0.f, 0.f, 0.f, 0.f};
  for (int k0 = 0; k0 < CIN; k0 += 32) {
    bf16x8 a0 = ldg8(xb + (size_t)(nA + lr) * CIN + k0 + quad * 8);
    bf16x8 a1 = ldg8(xb + (size_t)(nB + lr) * CIN + k0 + quad * 8);
#pragma unroll
    for (int ot = 0; ot < 4; ++ot) {
      bf16x8 bf = ldg8(Wb + (size_t)(ot * 16 + lr) * CIN + k0 + quad * 8);
      acc[0][ot] = MFMA(a0, bf, acc[0][ot]);
      acc[1][ot] = MFMA(a1, bf, acc[1][ot]);
    }
  }
  short* pb = phiT + (size_t)b * MM * C8;
  const int m0 = blockIdx.x * 32 + w * 8 + quad * 2;
#pragma unroll
  for (int ot = 0; ot < 4; ++ot) {
    float bia = bias[ot * 16 + lr];
    float vA0 = fmaxf(acc[0][ot][0] + bia, 0.f);
    float vA1 = fmaxf(acc[0][ot][1] + bia, 0.f);
    float vA2 = fmaxf(acc[0][ot][2] + bia, 0.f);
    float vA3 = fmaxf(acc[0][ot][3] + bia, 0.f);
    float vB0 = fmaxf(acc[1][ot][0] + bia, 0.f);
    float vB1 = fmaxf(acc[1][ot][1] + bia, 0.f);
    float vB2 = fmaxf(acc[1][ot][2] + bia, 0.f);
    float vB3 = fmaxf(acc[1][ot][3] + bia, 0.f);
    float q0 = fmaxf(fmaxf(vA0, vA1), fmaxf(vB0, vB1));
    float q1 = fmaxf(fmaxf(vA2, vA3), fmaxf(vB2, vB3));
    pb[(size_t)(m0 + 0) * C8 + ot * 16 + lr] = f2bf(q0);
    pb[(size_t)(m0 + 1) * C8 + ot * 16 + lr] = f2bf(q1);
  }
}

// ---------------------------------------------------------------------------
// g conv + fused pool: g_pool[b][c][m] bf16 (c-major)
// block: 64oc x 128n (rows h=2bx,2bx+1); wave: nA=w*16, nB=nA+64
// w-pair via shfl_xor(1) over lanes (col n adjacent); h-pair accA/accB
// ---------------------------------------------------------------------------
__global__ __launch_bounds__(256) void conv_g_pool_k(
    const short* __restrict__ xT, const short* __restrict__ Wg,
    const float* __restrict__ bias, short* __restrict__ gp) {
  const int t = threadIdx.x, w = t >> 6, l = t & 63;
  const int lr = l & 15, quad = l >> 4;
  const int nbase = blockIdx.x * 128;
  const int oc0 = blockIdx.y * 64;
  const int b = blockIdx.z;
  const short* xb = xT + (size_t)b * NPIX * CIN;
  const int nA = nbase + w * 16, nB = nA + 64;
  f32x4 acc[4][2];
#pragma unroll
  for (int i = 0; i < 4; ++i)
#pragma unroll
    for (int j = 0; j < 2; ++j) acc[i][j] = (f32x4){0.f, 0.f, 0.f, 0.f};
  for (int k0 = 0; k0 < CIN; k0 += 32) {
    bf16x8 b0 = ldg8(xb + (size_t)(nA + lr) * CIN + k0 + quad * 8);
    bf16x8 b1 = ldg8(xb + (size_t)(nB + lr) * CIN + k0 + quad * 8);
#pragma unroll
    for (int ot = 0; ot < 4; ++ot) {
      bf16x8 af = ldg8(Wg + (size_t)(oc0 + ot * 16 + lr) * CIN + k0 + quad * 8);
      acc[ot][0] = MFMA(af, b0, acc[ot][0]);
      acc[ot][1] = MFMA(af, b1, acc[ot][1]);
    }
  }
  short* gb = gp + (size_t)b * C2 * MM;
  const int m = blockIdx.x * 32 + ((w * 16 + lr) >> 1);
#pragma unroll
  for (int ot = 0; ot < 4; ++ot) {
#pragma unroll
    for (int r = 0; r < 4; ++r) {
      int oc = oc0 + ot * 16 + quad * 4 + r;
      float bia = bias[oc];
      float vA = fmaxf(acc[ot][0][r] + bia, 0.f);
      float vB = fmaxf(acc[ot][1][r] + bia, 0.f);
      float pA = fmaxf(vA, __shfl_xor(vA, 1));
      float pB = fmaxf(vB, __shfl_xor(vB, 1));
      float p = fmaxf(pA, pB);
      if ((l & 1) == 0) gb[(size_t)oc * MM + m] = f2bf(p);
    }
  }
}

// ---------------------------------------------------------------------------
// fused attention: per block (b, 16 queries n0..n0+15)
//  scores MFMA -> register softmax (cross-wave LDS reduce) -> beta bf16 LDS
//  -> PV MFMA -> o_pix (B,4096,256) bf16 pixel-major
// ---------------------------------------------------------------------------
__global__ __launch_bounds__(256) void attn_k(
    const short* __restrict__ thetaT, const short* __restrict__ phiT,
    const short* __restrict__ gp, short* __restrict__ o_pix) {
  __shared__ short beta_s[16 * 1032];   // row stride 1032 (pad: bank-friendly)
  __shared__ float red[2][4][16];
  const int t = threadIdx.x, w = t >> 6, l = t & 63;
  const int lr = l & 15, quad = l >> 4;
  const int b = blockIdx.y, n0 = blockIdx.x * 16;

  // ---- phase 1: scores 16n x 256m per wave ----
  const short* thb = thetaT + (size_t)b * NPIX * C8;
  const short* phb = phiT + (size_t)b * MM * C8;
  bf16x8 ta0 = ldg8(thb + (size_t)(n0 + lr) * C8 + quad * 8);
  bf16x8 ta1 = ldg8(thb + (size_t)(n0 + lr) * C8 + 32 + quad * 8);
  f32x4 sacc[16];
#pragma unroll
  for (int i = 0; i < 16; ++i) sacc[i] = (f32x4){0.f, 0.f, 0.f, 0.f};
#pragma unroll
  for (int mt = 0; mt < 16; ++mt) {
    int m = w * 256 + mt * 16;
    bf16x8 pb0 = ldg8(phb + (size_t)(m + lr) * C8 + quad * 8);
    bf16x8 pb1 = ldg8(phb + (size_t)(m + lr) * C8 + 32 + quad * 8);
    sacc[mt] = MFMA(ta0, pb0, sacc[mt]);
    sacc[mt] = MFMA(ta1, pb1, sacc[mt]);
  }

  // ---- phase 2: softmax over m (rows n = quad*4 + r) ----
  float mymax[4];
#pragma unroll
  for (int r = 0; r < 4; ++r) {
    float mx = sacc[0][r];
#pragma unroll
    for (int mt = 1; mt < 16; ++mt) mx = fmaxf(mx, sacc[mt][r]);
#pragma unroll
    for (int mask = 1; mask < 16; mask <<= 1) mx = fmaxf(mx, __shfl_xor(mx, mask));
    mymax[r] = mx;
  }
  if (lr == 0) {
#pragma unroll
    for (int r = 0; r < 4; ++r) red[0][w][quad * 4 + r] = mymax[r];
  }
  __syncthreads();
  float gmax[4];
#pragma unroll
  for (int r = 0; r < 4; ++r) {
    int nn = quad * 4 + r;
    gmax[r] = fmaxf(fmaxf(red[0][0][nn], red[0][1][nn]),
                    fmaxf(red[0][2][nn], red[0][3][nn]));
  }
  float mysum[4] = {0.f, 0.f, 0.f, 0.f};
#pragma unroll
  for (int mt = 0; mt < 16; ++mt) {
#pragma unroll
    for (int r = 0; r < 4; ++r) {
      float e = __expf(sacc[mt][r] - gmax[r]);
      sacc[mt][r] = e;
      mysum[r] += e;
    }
  }
#pragma unroll
  for (int r = 0; r < 4; ++r) {
#pragma unroll
    for (int mask = 1; mask < 16; mask <<= 1) mysum[r] += __shfl_xor(mysum[r], mask);
  }
  if (lr == 0) {
#pragma unroll
    for (int r = 0; r < 4; ++r) red[1][w][quad * 4 + r] = mysum[r];
  }
  __syncthreads();
#pragma unroll
  for (int r = 0; r < 4; ++r) {
    int nn = quad * 4 + r;
    float inv = 1.f / (red[1][0][nn] + red[1][1][nn] + red[1][2][nn] + red[1][3][nn]);
#pragma unroll
    for (int mt = 0; mt < 16; ++mt)
      beta_s[nn * 1032 + w * 256 + mt * 16 + lr] = f2bf(sacc[mt][r] * inv);
  }
  __syncthreads();

  // ---- phase 3: PV. wave w: c range [w*64, w*64+64) ----
  const short* gpb = gp + (size_t)b * C2 * MM;
  f32x4 oacc[4];
#pragma unroll
  for (int i = 0; i < 4; ++i) oacc[i] = (f32x4){0.f, 0.f, 0.f, 0.f};
  for (int kc = 0; kc < MM; kc += 32) {
    bf16x8 bb = *reinterpret_cast<const bf16x8*>(&beta_s[lr * 1032 + kc + quad * 8]);
#pragma unroll
    for (int ct = 0; ct < 4; ++ct) {
      bf16x8 ga = ldg8(gpb + (size_t)(w * 64 + ct * 16 + lr) * MM + kc + quad * 8);
      oacc[ct] = MFMA(ga, bb, oacc[ct]);
    }
  }
  short* ob = o_pix + (size_t)b * NPIX * C2 + (size_t)(n0 + lr) * C2;
#pragma unroll
  for (int ct = 0; ct < 4; ++ct) {
    int c0 = w * 64 + ct * 16 + quad * 4;
    short4 pk;
    pk.x = f2bf(oacc[ct][0]);
    pk.y = f2bf(oacc[ct][1]);
    pk.z = f2bf(oacc[ct][2]);
    pk.w = f2bf(oacc[ct][3]);
    *reinterpret_cast<short4*>(ob + c0) = pk;
  }
}

// ---------------------------------------------------------------------------
// final conv + gamma*relu + residual: out (B,512,4096) fp32
// block: 64oc x 128n; wave w: n-tiles {w*32, w*32+16}
// ---------------------------------------------------------------------------
__global__ __launch_bounds__(256) void conv_final_k(
    const short* __restrict__ o_pix, const short* __restrict__ Wo,
    const float* __restrict__ bo, const float* __restrict__ x,
    const float* __restrict__ gamma, float* __restrict__ out) {
  const int t = threadIdx.x, w = t >> 6, l = t & 63;
  const int lr = l & 15, quad = l >> 4;
  const int nbase = blockIdx.x * 128;
  const int oc0 = blockIdx.y * 64;
  const int b = blockIdx.z;
  const short* opb = o_pix + (size_t)b * NPIX * C2;
  const int nA = nbase + w * 32, nB = nA + 16;
  f32x4 acc[4][2];
#pragma unroll
  for (int i = 0; i < 4; ++i)
#pragma unroll
    for (int j = 0; j < 2; ++j) acc[i][j] = (f32x4){0.f, 0.f, 0.f, 0.f};
  for (int k0 = 0; k0 < C2; k0 += 32) {
    bf16x8 b0 = ldg8(opb + (size_t)(nA + lr) * C2 + k0 + quad * 8);
    bf16x8 b1 = ldg8(opb + (size_t)(nB + lr) * C2 + k0 + quad * 8);
#pragma unroll
    for (int ot = 0; ot < 4; ++ot) {
      bf16x8 af = ldg8(Wo + (size_t)(oc0 + ot * 16 + lr) * C2 + k0 + quad * 8);
      acc[ot][0] = MFMA(af, b0, acc[ot][0]);
      acc[ot][1] = MFMA(af, b1, acc[ot][1]);
    }
  }
  const float g0 = gamma[0];
#pragma unroll
  for (int ot = 0; ot < 4; ++ot) {
#pragma unroll
    for (int r = 0; r < 4; ++r) {
      int oc = oc0 + ot * 16 + quad * 4 + r;
      float bia = bo[oc];
      size_t base = ((size_t)(b * CIN + oc) << 12);
#pragma unroll
      for (int nt = 0; nt < 2; ++nt) {
        int n = (nt ? nB : nA) + lr;
        float v = fmaxf(acc[ot][nt][r] + bia, 0.f);
        out[base + n] = g0 * v + x[base + n];
      }
    }
  }
}

// ---------------------------------------------------------------------------
extern "C" void kernel_launch(void* const* d_in, const int* in_sizes, int n_in,
                              void* d_out, int out_size, void* d_ws, size_t ws_size,
                              hipStream_t stream) {
  const float* x       = (const float*)d_in[0];
  const float* W_theta = (const float*)d_in[1];
  const float* b_theta = (const float*)d_in[2];
  const float* W_phi   = (const float*)d_in[3];
  const float* b_phi   = (const float*)d_in[4];
  const float* W_g     = (const float*)d_in[5];
  const float* b_g     = (const float*)d_in[6];
  const float* W_o     = (const float*)d_in[7];
  const float* b_o     = (const float*)d_in[8];
  const float* gamma   = (const float*)d_in[9];
  float* out = (float*)d_out;
  char* W = (char*)d_ws;

  // workspace layout (bytes):
  short* xT     = (short*)(W);              // 67,108,864 (B,4096,512) bf16
  short* o_pix  = (short*)(W);              // aliases xT (dead after g conv)
  short* wbf    = (short*)(W + 67108864);   // 655,360: wth|wph|wg|wo
  short* thetaT = (short*)(W + 67764224);   // 8,388,608 (B,4096,64)
  short* phiT   = (short*)(W + 76152832);   // 2,097,152 (B,1024,64)
  short* gp     = (short*)(W + 78249984);   // 8,388,608 (B,256,1024)
  // total 86,638,592 bytes
  short* wth = wbf;
  short* wph = wbf + 32768;
  short* wg  = wbf + 65536;
  short* wo  = wbf + 196608;

  cast_x_k<<<dim3(64, 8, 16), 256, 0, stream>>>(x, xT);
  cast_w_k<<<dim3(1280), 256, 0, stream>>>(W_theta, W_phi, W_g, W_o, wbf);
  conv_theta_k<<<dim3(32, 16), 256, 0, stream>>>(xT, wth, b_theta, thetaT);
  conv_phi_pool_k<<<dim3(32, 16), 256, 0, stream>>>(xT, wph, b_phi, phiT);
  conv_g_pool_k<<<dim3(32, 4, 16), 256, 0, stream>>>(xT, wg, b_g, gp);
  attn_k<<<dim3(256, 16), 256, 0, stream>>>(thetaT, phiT, gp, o_pix);
  conv_final_k<<<dim3(32, 8, 16), 256, 0, stream>>>(o_pix, wo, b_o, x, gamma, out);
}

// Round 3
// 640.853 us; speedup vs baseline: 4.8720x; 1.2975x over previous
//
#include <hip/hip_runtime.h>
#include <cstdint>
#include <cstddef>

#define BB 16
#define CIN 512
#define NPIX 4096   // 64*64
#define C8 64
#define C2 256
#define MM 1024     // pooled positions 32*32

using bf16x8 = __attribute__((ext_vector_type(8))) short;
using f32x4  = __attribute__((ext_vector_type(4))) float;

__device__ __forceinline__ short f2bf(float f) {
  union { float f; unsigned u; } v; v.f = f;
  unsigned r = v.u + 0x7FFFu + ((v.u >> 16) & 1u);
  return (short)(r >> 16);
}
__device__ __forceinline__ bf16x8 ldg8(const short* p) {
  return *reinterpret_cast<const bf16x8*>(p);
}
__device__ __forceinline__ bf16x8 lds8(const short* p) {  // 8B-aligned LDS read
  union { unsigned long long q[2]; bf16x8 v; } u;
  u.q[0] = *reinterpret_cast<const unsigned long long*>(p);
  u.q[1] = *reinterpret_cast<const unsigned long long*>(p + 4);
  return u.v;
}
#define MFMA(a, b, c) __builtin_amdgcn_mfma_f32_16x16x32_bf16(a, b, c, 0, 0, 0)

// ---------------------------------------------------------------------------
// weight casts: Wtheta(32768) | Wphi(32768) | Wg(131072) | Wo(131072) floats
// ---------------------------------------------------------------------------
__global__ __launch_bounds__(256) void cast_w_k(const float* __restrict__ wa,
                                                const float* __restrict__ wb,
                                                const float* __restrict__ wc,
                                                const float* __restrict__ wd,
                                                short* __restrict__ out) {
  int i = blockIdx.x * 256 + threadIdx.x;
  float v;
  if (i < 32768) v = wa[i];
  else if (i < 65536) v = wb[i - 32768];
  else if (i < 196608) v = wc[i - 65536];
  else v = wd[i - 196608];
  out[i] = f2bf(v);
}

// ---------------------------------------------------------------------------
// conv_mega: x fp32 (B,512,4096) -> thetaT (B,4096,64), phiT (B,1024,64),
//            gp (B,256,1024)   all bf16, relu, phi/g 2x2-maxpooled.
// 512 threads. Block = 128 pixels (2 image rows h=2bx,2bx+1) x 384 oc.
// Wave w handles oc [48w, 48w+48). K-loop c in chunks of 32 staged via LDS
// (fp32->bf16 + transpose), register-prefetched.
// ---------------------------------------------------------------------------
__global__ __launch_bounds__(512) void conv_mega_k(
    const float* __restrict__ x, const short* __restrict__ wbf,
    const float* __restrict__ bth, const float* __restrict__ bph,
    const float* __restrict__ bg,
    short* __restrict__ thetaT, short* __restrict__ phiT,
    short* __restrict__ gp) {
  __shared__ __align__(16) short xs[128][36];   // stride 72B: 8B-aligned rows
  const int t = threadIdx.x, w = t >> 6, l = t & 63;
  const int lr = l & 15, quad = l >> 4;
  const int bx = blockIdx.x, b = blockIdx.y;
  const int nbase = bx * 128;
  const float* xb = x + ((size_t)b * CIN << 12) + nbase;

  // staging mapping: nl = t&127, cp = t>>7 (0..3); pairs p: cl = (p*4+cp)*2
  const int nl = t & 127, cp = t >> 7;

  f32x4 acc[3][8];
#pragma unroll
  for (int i = 0; i < 3; ++i)
#pragma unroll
    for (int j = 0; j < 8; ++j) acc[i][j] = (f32x4){0.f, 0.f, 0.f, 0.f};

  // prefetch chunk 0
  float pv0[4], pv1[4];
#pragma unroll
  for (int p = 0; p < 4; ++p) {
    int cl = (p * 4 + cp) * 2;
    pv0[p] = xb[((size_t)cl << 12) + nl];
    pv1[p] = xb[((size_t)(cl + 1) << 12) + nl];
  }

  for (int c0 = 0; c0 < CIN; c0 += 32) {
    __syncthreads();   // previous chunk's reads complete
#pragma unroll
    for (int p = 0; p < 4; ++p) {
      int cl = (p * 4 + cp) * 2;
      unsigned pk = (unsigned)(unsigned short)f2bf(pv0[p]) |
                    ((unsigned)(unsigned short)f2bf(pv1[p]) << 16);
      *reinterpret_cast<unsigned*>(&xs[nl][cl]) = pk;
    }
    __syncthreads();   // xs ready
    if (c0 + 32 < CIN) {
#pragma unroll
      for (int p = 0; p < 4; ++p) {
        int cl = (p * 4 + cp) * 2;
        pv0[p] = xb[((size_t)(c0 + 32 + cl) << 12) + nl];
        pv1[p] = xb[((size_t)(c0 + 32 + cl + 1) << 12) + nl];
      }
    }
    bf16x8 af[3];
#pragma unroll
    for (int tt = 0; tt < 3; ++tt)
      af[tt] = ldg8(wbf + (size_t)(w * 48 + tt * 16 + lr) * CIN + c0 + quad * 8);
#pragma unroll
    for (int nt = 0; nt < 8; ++nt) {
      bf16x8 bfr = lds8(&xs[nt * 16 + lr][quad * 8]);
#pragma unroll
      for (int tt = 0; tt < 3; ++tt)
        acc[tt][nt] = MFMA(af[tt], bfr, acc[tt][nt]);
    }
  }

  // epilogue per tile
#pragma unroll
  for (int tt = 0; tt < 3; ++tt) {
    const int ocb = w * 48 + tt * 16;
    if (ocb < 64) {           // theta: no pool, (n, 64) layout
      short* tb = thetaT + ((size_t)b << 12) * C8;
#pragma unroll
      for (int r = 0; r < 4; ++r) {
        int oc = ocb + quad * 4 + r;
        float bia = bth[oc];
#pragma unroll
        for (int nt = 0; nt < 8; ++nt) {
          int n = nbase + nt * 16 + lr;
          tb[(size_t)n * C8 + oc] = f2bf(fmaxf(acc[tt][nt][r] + bia, 0.f));
        }
      }
    } else if (ocb < 128) {   // phi: pool, (m, 64) layout
      short* pb = phiT + ((size_t)b << 10) * C8;
#pragma unroll
      for (int r = 0; r < 4; ++r) {
        int oc = ocb - 64 + quad * 4 + r;
        float bia = bph[oc];
#pragma unroll
        for (int nt = 0; nt < 4; ++nt) {
          float va = fmaxf(acc[tt][nt][r] + bia, 0.f);
          float vb = fmaxf(acc[tt][nt + 4][r] + bia, 0.f);
          float pa = fmaxf(va, __shfl_xor(va, 1));
          float pbv = fmaxf(vb, __shfl_xor(vb, 1));
          float pool = fmaxf(pa, pbv);
          if ((l & 1) == 0) {
            int m = bx * 32 + nt * 8 + (lr >> 1);
            pb[(size_t)m * C8 + oc] = f2bf(pool);
          }
        }
      }
    } else {                  // g: pool, (256, 1024) c-major layout
      short* gb = gp + ((size_t)b << 10) * C2;
#pragma unroll
      for (int r = 0; r < 4; ++r) {
        int oc = ocb - 128 + quad * 4 + r;
        float bia = bg[oc];
#pragma unroll
        for (int nt = 0; nt < 4; ++nt) {
          float va = fmaxf(acc[tt][nt][r] + bia, 0.f);
          float vb = fmaxf(acc[tt][nt + 4][r] + bia, 0.f);
          float pa = fmaxf(va, __shfl_xor(va, 1));
          float pbv = fmaxf(vb, __shfl_xor(vb, 1));
          float pool = fmaxf(pa, pbv);
          if ((l & 1) == 0) {
            int m = bx * 32 + nt * 8 + (lr >> 1);
            gb[(size_t)oc * MM + m] = f2bf(pool);
          }
        }
      }
    }
  }
}

// ---------------------------------------------------------------------------
// attn_flash: per block (b, 64 queries). Wave w owns queries [q0+16w, +16) for
// scores/softmax (flash over 4 m-chunks of 256); PV splits waves by channel
// (wave w: c in [64w, 64w+64)) with p shared via LDS. Epilogue: fused final
// conv (Wo 512x256) + gamma*relu + residual, o round-trips through LDS.
// ---------------------------------------------------------------------------
__global__ __launch_bounds__(256) void attn_k(
    const short* __restrict__ thetaT, const short* __restrict__ phiT,
    const short* __restrict__ gp, const short* __restrict__ wo,
    const float* __restrict__ bo, const float* __restrict__ x,
    const float* __restrict__ gamma, float* __restrict__ out) {
  __shared__ __align__(16) short ps[4][16][264];   // p (16n x 256m)/wave; reused as o (64n x 256c)
  __shared__ float balpha[4][16];
  __shared__ float binv[4][16];
  const int t = threadIdx.x, w = t >> 6, l = t & 63;
  const int lr = l & 15, quad = l >> 4;
  const int b = blockIdx.y, q0 = blockIdx.x * 64, n0 = q0 + w * 16;

  const short* thb = thetaT + ((size_t)b << 12) * C8;
  const short* phb = phiT + ((size_t)b << 10) * C8;
  const short* gpb = gp + ((size_t)b << 10) * C2;

  bf16x8 ta0 = ldg8(thb + (size_t)(n0 + lr) * C8 + quad * 8);
  bf16x8 ta1 = ldg8(thb + (size_t)(n0 + lr) * C8 + 32 + quad * 8);

  f32x4 oacc[4][4];   // [ct][qt]: c = 64w+16ct+quad*4+reg, n = q0+16qt+lr
#pragma unroll
  for (int i = 0; i < 4; ++i)
#pragma unroll
    for (int j = 0; j < 4; ++j) oacc[i][j] = (f32x4){0.f, 0.f, 0.f, 0.f};
  float mrun[4] = {-3e38f, -3e38f, -3e38f, -3e38f};
  float ssum[4] = {0.f, 0.f, 0.f, 0.f};

  for (int ci = 0; ci < 4; ++ci) {
    // ---- scores for own 16 queries x 256 m ----
    f32x4 sacc[16];
#pragma unroll
    for (int i = 0; i < 16; ++i) sacc[i] = (f32x4){0.f, 0.f, 0.f, 0.f};
#pragma unroll
    for (int mt = 0; mt < 16; ++mt) {
      int m = ci * 256 + mt * 16;
      bf16x8 pb0 = ldg8(phb + (size_t)(m + lr) * C8 + quad * 8);
      bf16x8 pb1 = ldg8(phb + (size_t)(m + lr) * C8 + 32 + quad * 8);
      sacc[mt] = MFMA(ta0, pb0, sacc[mt]);
      sacc[mt] = MFMA(ta1, pb1, sacc[mt]);
    }
    // ---- online softmax update (rows n = quad*4 + r) ----
    float mnew[4], alpha[4], rp[4];
#pragma unroll
    for (int r = 0; r < 4; ++r) {
      float cx = sacc[0][r];
#pragma unroll
      for (int mt = 1; mt < 16; ++mt) cx = fmaxf(cx, sacc[mt][r]);
#pragma unroll
      for (int mask = 1; mask < 16; mask <<= 1) cx = fmaxf(cx, __shfl_xor(cx, mask));
      mnew[r] = fmaxf(mrun[r], cx);
      alpha[r] = __expf(mrun[r] - mnew[r]);
      mrun[r] = mnew[r];
      rp[r] = 0.f;
    }
    __syncthreads();   // all waves finished reading prev chunk's ps/balpha
#pragma unroll
    for (int mt = 0; mt < 16; ++mt) {
#pragma unroll
      for (int r = 0; r < 4; ++r) {
        float e = __expf(sacc[mt][r] - mnew[r]);
        rp[r] += e;
        ps[w][quad * 4 + r][mt * 16 + lr] = f2bf(e);
      }
    }
#pragma unroll
    for (int r = 0; r < 4; ++r) ssum[r] = ssum[r] * alpha[r] + rp[r];
    if (lr == 0) {
#pragma unroll
      for (int r = 0; r < 4; ++r) balpha[w][quad * 4 + r] = alpha[r];
    }
    __syncthreads();   // ps + balpha ready
    float av[4];
#pragma unroll
    for (int qt = 0; qt < 4; ++qt) av[qt] = balpha[qt][lr];
#pragma unroll
    for (int ct = 0; ct < 4; ++ct)
#pragma unroll
      for (int qt = 0; qt < 4; ++qt) oacc[ct][qt] *= av[qt];
    // ---- PV: wave w covers c [64w, +64), all 64 queries ----
#pragma unroll
    for (int kc = 0; kc < 8; ++kc) {
      bf16x8 pf[4];
#pragma unroll
      for (int qt = 0; qt < 4; ++qt)
        pf[qt] = *reinterpret_cast<const bf16x8*>(&ps[qt][lr][kc * 32 + quad * 8]);
#pragma unroll
      for (int ct = 0; ct < 4; ++ct) {
        bf16x8 ga = ldg8(gpb + (size_t)(w * 64 + ct * 16 + lr) * MM +
                         ci * 256 + kc * 32 + quad * 8);
#pragma unroll
        for (int qt = 0; qt < 4; ++qt)
          oacc[ct][qt] = MFMA(ga, pf[qt], oacc[ct][qt]);
      }
    }
  }

  // ---- final softmax denominators ----
#pragma unroll
  for (int r = 0; r < 4; ++r) {
    float sv = ssum[r];
#pragma unroll
    for (int mask = 1; mask < 16; mask <<= 1) sv += __shfl_xor(sv, mask);
    if (lr == 0) binv[w][quad * 4 + r] = 1.f / sv;
  }
  __syncthreads();   // all PV done (safe to overwrite ps as o), binv ready
  float invn[4];
#pragma unroll
  for (int qt = 0; qt < 4; ++qt) invn[qt] = binv[qt][lr];

  // ---- write o to LDS as (64n x 256c), rows n-local = 16qt+lr ----
  short (*os)[264] = reinterpret_cast<short (*)[264]>(ps);
#pragma unroll
  for (int ct = 0; ct < 4; ++ct) {
    int c0 = w * 64 + ct * 16 + quad * 4;
#pragma unroll
    for (int qt = 0; qt < 4; ++qt) {
      short4 pk;
      pk.x = f2bf(oacc[ct][qt][0] * invn[qt]);
      pk.y = f2bf(oacc[ct][qt][1] * invn[qt]);
      pk.z = f2bf(oacc[ct][qt][2] * invn[qt]);
      pk.w = f2bf(oacc[ct][qt][3] * invn[qt]);
      *reinterpret_cast<short4*>(&os[qt * 16 + lr][c0]) = pk;
    }
  }
  __syncthreads();   // os complete

  // ---- fused final conv: wave w -> oc [128w, +128) ----
  f32x4 acc2[8][4];
#pragma unroll
  for (int i = 0; i < 8; ++i)
#pragma unroll
    for (int j = 0; j < 4; ++j) acc2[i][j] = (f32x4){0.f, 0.f, 0.f, 0.f};
#pragma unroll
  for (int kc = 0; kc < 8; ++kc) {
    bf16x8 of[4];
#pragma unroll
    for (int qt = 0; qt < 4; ++qt)
      of[qt] = *reinterpret_cast<const bf16x8*>(&os[qt * 16 + lr][kc * 32 + quad * 8]);
#pragma unroll
    for (int ot = 0; ot < 8; ++ot) {
      bf16x8 wa = ldg8(wo + (size_t)(w * 128 + ot * 16 + lr) * C2 +
                       kc * 32 + quad * 8);
#pragma unroll
      for (int qt = 0; qt < 4; ++qt)
        acc2[ot][qt] = MFMA(wa, of[qt], acc2[ot][qt]);
    }
  }
  const float g0 = gamma[0];
#pragma unroll
  for (int ot = 0; ot < 8; ++ot) {
#pragma unroll
    for (int r = 0; r < 4; ++r) {
      int oc = w * 128 + ot * 16 + quad * 4 + r;
      float bia = bo[oc];
      size_t base = ((size_t)(b * CIN + oc) << 12);
#pragma unroll
      for (int qt = 0; qt < 4; ++qt) {
        int n = q0 + qt * 16 + lr;
        float v = g0 * fmaxf(acc2[ot][qt][r] + bia, 0.f);
        out[base + n] = v + x[base + n];
      }
    }
  }
}

// ---------------------------------------------------------------------------
extern "C" void kernel_launch(void* const* d_in, const int* in_sizes, int n_in,
                              void* d_out, int out_size, void* d_ws, size_t ws_size,
                              hipStream_t stream) {
  const float* x       = (const float*)d_in[0];
  const float* W_theta = (const float*)d_in[1];
  const float* b_theta = (const float*)d_in[2];
  const float* W_phi   = (const float*)d_in[3];
  const float* b_phi   = (const float*)d_in[4];
  const float* W_g     = (const float*)d_in[5];
  const float* b_g     = (const float*)d_in[6];
  const float* W_o     = (const float*)d_in[7];
  const float* b_o     = (const float*)d_in[8];
  const float* gamma   = (const float*)d_in[9];
  float* out = (float*)d_out;
  char* W = (char*)d_ws;

  // workspace (bytes): thetaT 8,388,608 | phiT 2,097,152 | gp 8,388,608 | wbf 655,360
  short* thetaT = (short*)(W);
  short* phiT   = (short*)(W + 8388608);
  short* gp     = (short*)(W + 10485760);
  short* wbf    = (short*)(W + 18874368);
  short* wo     = wbf + 196608;

  cast_w_k<<<dim3(1280), 256, 0, stream>>>(W_theta, W_phi, W_g, W_o, wbf);
  conv_mega_k<<<dim3(32, 16), 512, 0, stream>>>(x, wbf, b_theta, b_phi, b_g,
                                                thetaT, phiT, gp);
  attn_k<<<dim3(64, 16), 256, 0, stream>>>(thetaT, phiT, gp, wo, b_o, x, gamma, out);
}